// Round 12
// baseline (300.837 us; speedup 1.0000x reference)
//
#include <hip/hip_runtime.h>
#include <hip/hip_bf16.h>

#define D_MODEL 128
#define SEQ_L   4096
#define BATCH   128
#define NSTRIP  2                    // strips per batch row
#define STRIP   (SEQ_L / NSTRIP)     // 2048 tokens per strip
#define NBLK    (BATCH * NSTRIP)     // 256 blocks = 1/CU -> barrier deadlock-safe

typedef float f4 __attribute__((ext_vector_type(4)));
typedef float f32x4 __attribute__((ext_vector_type(4)));
typedef short bf16x8 __attribute__((ext_vector_type(8)));

__device__ __forceinline__ unsigned short f2bf(float f) {
    union { float f; unsigned u; } v; v.f = f;
    unsigned r = v.u + 0x7FFFu + ((v.u >> 16) & 1u);
    return (unsigned short)(r >> 16);
}

// device-scope grid barrier; ctr zeroed by hipMemsetAsync before every launch
__device__ __forceinline__ void gridbar(int* ctr) {
    __syncthreads();
    if (threadIdx.x == 0) {
        __threadfence();                       // release
        atomicAdd(ctr, 1);
        while (__hip_atomic_load(ctr, __ATOMIC_ACQUIRE, __HIP_MEMORY_SCOPE_AGENT) < NBLK)
            __builtin_amdgcn_s_sleep(1);
    }
    __syncthreads();
    __threadfence();                           // acquire
}

template<bool GUARD>
__device__ __forceinline__ void load6(const float* __restrict__ xb, int gr0, int c4, f4 R[6]) {
    #pragma unroll
    for (int j = 0; j < 6; ++j) {
        int gr = gr0 + j;
        if (GUARD) {
            bool ok = (gr >= 0) && (gr < SEQ_L);
            int grc = ok ? gr : 0;
            f4 v = reinterpret_cast<const f4*>(xb + (size_t)grc * D_MODEL)[c4];
            f4 z = {0.f, 0.f, 0.f, 0.f};
            R[j] = ok ? v : z;
        } else {
            R[j] = reinterpret_cast<const f4*>(xb + (size_t)gr * D_MODEL)[c4];
        }
    }
}

// 256 blocks x 1024 threads = 16 waves/CU (4/SIMD), 1 block/CU.
__global__ __launch_bounds__(1024, 4) void fused(const float* __restrict__ x,
                                                 const float* __restrict__ W1,
                                                 const float* __restrict__ b1,
                                                 const float* __restrict__ W2,
                                                 const float* __restrict__ b2,
                                                 const float* __restrict__ Wc,
                                                 const float* __restrict__ bc,
                                                 float* __restrict__ out,
                                                 int* __restrict__ ctr,
                                                 float* __restrict__ part) {
    __shared__ __align__(16) unsigned short y_lds[2][128][132];   // 67.6 KB (aliased by red)
    __shared__ __align__(16) float wv_lds[3][128];

    const int t = threadIdx.x, gid = blockIdx.x;
    const int b = gid >> 1, strip = gid & 1;
    const int sb = strip * STRIP;
    const float* xb = x + (size_t)b * SEQ_L * D_MODEL;
    float* outb = out + (size_t)b * SEQ_L * D_MODEL;

    // ============ phase 1: partial mean of own 2048-token strip ============
    {
        int c4 = t & 31, ph = t >> 5;            // ph 0..31
        const f4* xv = reinterpret_cast<const f4*>(xb);
        f4 acc = {0.f, 0.f, 0.f, 0.f};
        #pragma unroll
        for (int o = 0; o < 8; ++o) {            // 8 x 256 tokens
            f4 R[8];
            #pragma unroll
            for (int j = 0; j < 8; ++j)
                R[j] = xv[(size_t)(sb + o * 256 + ph + j * 32) * 32 + c4];
            R[0] += R[4]; R[1] += R[5]; R[2] += R[6]; R[3] += R[7];
            R[0] += R[2]; R[1] += R[3];
            acc += R[0] + R[1];
        }
        f4* red = reinterpret_cast<f4*>(y_lds);  // 16 KB scratch inside y_lds
        red[t] = acc;
        __syncthreads();
        if (t < 32) {
            f4 s = red[t];
            #pragma unroll
            for (int p = 1; p < 32; ++p) s += red[t + 32 * p];
            reinterpret_cast<f4*>(part + ((size_t)b * NSTRIP + strip) * D_MODEL)[t] = s;
        }
    }
    gridbar(ctr);   // part complete, visible device-wide

    // ============ phase 2: every block redundantly computes wv[3][128] -> LDS ============
    if (t < 512) {
        int c = t >> 2, p = t & 3;
        f4 mv[8];
        #pragma unroll
        for (int d4 = 0; d4 < 8; ++d4) mv[d4] = (f4){0.f, 0.f, 0.f, 0.f};
        #pragma unroll
        for (int s = 0; s < NSTRIP; ++s) {
            const f4* ps = reinterpret_cast<const f4*>(part + ((size_t)c * NSTRIP + s) * D_MODEL + p * 32);
            #pragma unroll
            for (int d4 = 0; d4 < 8; ++d4) mv[d4] += ps[d4];
        }
        #pragma unroll
        for (int d4 = 0; d4 < 8; ++d4) mv[d4] *= (1.0f / (float)SEQ_L);

        float h[32];
        #pragma unroll
        for (int j = 0; j < 32; ++j) {
            const f4* w1r = reinterpret_cast<const f4*>(W1 + j * 128 + p * 32);
            f4 s4 = {0.f, 0.f, 0.f, 0.f};
            #pragma unroll
            for (int d4 = 0; d4 < 8; ++d4) s4 += mv[d4] * w1r[d4];
            float s = s4[0] + s4[1] + s4[2] + s4[3];
            s += __shfl_xor(s, 1);
            s += __shfl_xor(s, 2);               // full 128-dot across 4 partners
            s += b1[j];
            h[j] = 0.5f * s * (1.0f + erff(s * 0.70710678118654752f)); // exact gelu
        }
        if (p == 0) {
            float lg[3], mx = -1e30f;
            #pragma unroll
            for (int k = 0; k < 3; ++k) {
                float s = b2[k];
                #pragma unroll
                for (int j = 0; j < 32; ++j) s += h[j] * W2[k * 32 + j];
                lg[k] = s; mx = fmaxf(mx, s);
            }
            float e[3], den = 0.f;
            #pragma unroll
            for (int k = 0; k < 3; ++k) { e[k] = __expf(lg[k] - mx); den += e[k]; }
            float inv = 1.0f / den;
            #pragma unroll
            for (int k = 0; k < 3; ++k) wv_lds[k][c] = e[k] * inv;
        }
    }
    __syncthreads();   // wv_lds ready

    // ============ phase 3: conv + MFMA on own strip, 128-token tiles, 16 waves ============
    {
        int c4 = t & 31, rg = t >> 5;            // rg 0..31: rows rg*4..rg*4+3 of tile
        int lane = t & 63, wid = t >> 6;         // wid 0..15
        int r = lane & 15, q = lane >> 4, kb = q * 8;
        int hh = wid >> 3;                       // token half (0: rows 0-63, 1: 64-127)
        int co0 = (wid & 7) * 16;                // co block

        f4 w0 = *reinterpret_cast<const f4*>(&wv_lds[0][c4 * 4]);
        f4 w1 = *reinterpret_cast<const f4*>(&wv_lds[1][c4 * 4]);
        f4 w2 = *reinterpret_cast<const f4*>(&wv_lds[2][c4 * 4]);

        // Wc A-fragments from fp32 (L2/L3-hot), cvt in registers
        bf16x8 awc[4];
        #pragma unroll
        for (int kc = 0; kc < 4; ++kc) {
            const float* wr = Wc + (size_t)(co0 + r) * D_MODEL + kc * 32 + kb;
            f4 a = *reinterpret_cast<const f4*>(wr);
            f4 bb = *reinterpret_cast<const f4*>(wr + 4);
            bf16x8 fr;
            fr[0] = (short)f2bf(a[0]); fr[1] = (short)f2bf(a[1]);
            fr[2] = (short)f2bf(a[2]); fr[3] = (short)f2bf(a[3]);
            fr[4] = (short)f2bf(bb[0]); fr[5] = (short)f2bf(bb[1]);
            fr[6] = (short)f2bf(bb[2]); fr[7] = (short)f2bf(bb[3]);
            awc[kc] = fr;
        }

        f4 bcv = *reinterpret_cast<const f4*>(bc + co0 + q * 4);

        f4 R[6];
        if (sb == 0) load6<true>(xb, sb + rg * 4 - 1, c4, R);   // token -1 guard
        else         load6<false>(xb, sb + rg * 4 - 1, c4, R);

        for (int ht = 0; ht < STRIP / 128; ++ht) {   // 16 tiles of 128 tokens
            const int buf = ht & 1;
            int base = sb + ht * 128;
            // conv (consumes R) + LDS write
            #pragma unroll
            for (int j = 0; j < 4; ++j) {
                f4 y = R[j] * w0 + R[j + 1] * w1 + R[j + 2] * w2;
                ushort4 yb;
                yb.x = f2bf(y[0]); yb.y = f2bf(y[1]); yb.z = f2bf(y[2]); yb.w = f2bf(y[3]);
                *reinterpret_cast<ushort4*>(&y_lds[buf][rg * 4 + j][c4 * 4]) = yb;
            }
            // issue next tile's loads (fly under barrier+MFMA+stores)
            if (ht < STRIP / 128 - 1) {
                int nb = base + 128;
                if (nb + 128 == SEQ_L) load6<true>(xb, nb + rg * 4 - 1, c4, R);  // token 4096 guard
                else                   load6<false>(xb, nb + rg * 4 - 1, c4, R);
            }
            __syncthreads();   // y_lds[buf] visible

            // MFMA: wave = 64 tokens (half hh) x 16 co
            f32x4 acc[4];
            #pragma unroll
            for (int g = 0; g < 4; ++g) acc[g] = (f32x4){0.f, 0.f, 0.f, 0.f};
            #pragma unroll
            for (int g = 0; g < 4; ++g)
                #pragma unroll
                for (int kc = 0; kc < 4; ++kc) {
                    bf16x8 bv = *reinterpret_cast<const bf16x8*>(
                        &y_lds[buf][hh * 64 + g * 16 + r][kc * 32 + kb]);
                    acc[g] = __builtin_amdgcn_mfma_f32_16x16x32_bf16(awc[kc], bv, acc[g], 0, 0, 0);
                }

            #pragma unroll
            for (int g = 0; g < 4; ++g) {
                int tok = base + hh * 64 + g * 16 + r;
                *reinterpret_cast<f4*>(outb + (size_t)tok * D_MODEL + co0 + q * 4) = acc[g] + bcv;
            }
            __syncthreads();   // all waves done with y_lds[buf] before rewrite
        }
    }
}

extern "C" void kernel_launch(void* const* d_in, const int* in_sizes, int n_in,
                              void* d_out, int out_size, void* d_ws, size_t ws_size,
                              hipStream_t stream) {
    const float* x  = (const float*)d_in[0];
    const float* W1 = (const float*)d_in[1];
    const float* b1 = (const float*)d_in[2];
    const float* W2 = (const float*)d_in[3];
    const float* b2 = (const float*)d_in[4];
    const float* Wc = (const float*)d_in[5];
    const float* bc = (const float*)d_in[6];
    float* out = (float*)d_out;

    char* ws = (char*)d_ws;
    int* ctr = (int*)ws;                                      // barrier counter (zeroed below)
    float* part = (float*)(ws + 1024);                        // 128*2*128*4 = 128 KB

    hipMemsetAsync(ctr, 0, 128, stream);   // reset barrier counter every call (graph-legal)
    fused<<<NBLK, 1024, 0, stream>>>(x, W1, b1, W2, b2, Wc, bc, out, ctr, part);
}

// Round 13
// 299.669 us; speedup vs baseline: 1.0039x; 1.0039x over previous
//
#include <hip/hip_runtime.h>
#include <hip/hip_bf16.h>

#define D_MODEL 128
#define SEQ_L   4096
#define BATCH   128
#define NSTRIP  2                    // strips per batch row
#define STRIP   (SEQ_L / NSTRIP)     // 2048 tokens per strip
#define NBLK    (BATCH * NSTRIP)     // 256 blocks = 1/CU -> barrier deadlock-safe

typedef float f4 __attribute__((ext_vector_type(4)));
typedef float f32x4 __attribute__((ext_vector_type(4)));
typedef short bf16x8 __attribute__((ext_vector_type(8)));

__device__ __forceinline__ unsigned short f2bf(float f) {
    union { float f; unsigned u; } v; v.f = f;
    unsigned r = v.u + 0x7FFFu + ((v.u >> 16) & 1u);
    return (unsigned short)(r >> 16);
}

// device-scope grid barrier; ctr zeroed by hipMemsetAsync before every launch
__device__ __forceinline__ void gridbar(int* ctr) {
    __syncthreads();
    if (threadIdx.x == 0) {
        __threadfence();                       // release
        atomicAdd(ctr, 1);
        while (__hip_atomic_load(ctr, __ATOMIC_ACQUIRE, __HIP_MEMORY_SCOPE_AGENT) < NBLK)
            __builtin_amdgcn_s_sleep(1);
    }
    __syncthreads();
    __threadfence();                           // acquire
}

template<bool GUARD>
__device__ __forceinline__ void load6(const float* __restrict__ xb, int gr0, int c4, f4 R[6]) {
    #pragma unroll
    for (int j = 0; j < 6; ++j) {
        int gr = gr0 + j;
        if (GUARD) {
            bool ok = (gr >= 0) && (gr < SEQ_L);
            int grc = ok ? gr : 0;
            f4 v = reinterpret_cast<const f4*>(xb + (size_t)grc * D_MODEL)[c4];
            f4 z = {0.f, 0.f, 0.f, 0.f};
            R[j] = ok ? v : z;
        } else {
            R[j] = reinterpret_cast<const f4*>(xb + (size_t)gr * D_MODEL)[c4];
        }
    }
}

// 256 blocks x 1024 threads = 16 waves/CU (4/SIMD), 1 block/CU.
// Single-arg launch_bounds: 16 waves/block forces VGPR cap 128 (not 64) — r9/r12
// showed a second arg of 4 caps the allocator at 64 VGPR and spills to scratch.
__global__ __launch_bounds__(1024) void fused(const float* __restrict__ x,
                                              const float* __restrict__ W1,
                                              const float* __restrict__ b1,
                                              const float* __restrict__ W2,
                                              const float* __restrict__ b2,
                                              const float* __restrict__ Wc,
                                              const float* __restrict__ bc,
                                              float* __restrict__ out,
                                              int* __restrict__ ctr,
                                              float* __restrict__ part) {
    __shared__ __align__(16) unsigned short y_lds[2][128][132];   // 67.6 KB (aliased by red)
    __shared__ __align__(16) float wv_lds[3][128];

    const int t = threadIdx.x, gid = blockIdx.x;
    const int b = gid >> 1, strip = gid & 1;
    const int sb = strip * STRIP;
    const float* xb = x + (size_t)b * SEQ_L * D_MODEL;
    float* outb = out + (size_t)b * SEQ_L * D_MODEL;

    // ============ phase 1: partial mean of own 2048-token strip ============
    {
        int c4 = t & 31, ph = t >> 5;            // ph 0..31
        const f4* xv = reinterpret_cast<const f4*>(xb);
        f4 acc = {0.f, 0.f, 0.f, 0.f};
        #pragma unroll
        for (int o = 0; o < 8; ++o) {            // 8 x 256 tokens
            f4 R[8];
            #pragma unroll
            for (int j = 0; j < 8; ++j)
                R[j] = xv[(size_t)(sb + o * 256 + ph + j * 32) * 32 + c4];
            R[0] += R[4]; R[1] += R[5]; R[2] += R[6]; R[3] += R[7];
            R[0] += R[2]; R[1] += R[3];
            acc += R[0] + R[1];
        }
        f4* red = reinterpret_cast<f4*>(y_lds);  // 16 KB scratch inside y_lds
        red[t] = acc;
        __syncthreads();
        if (t < 32) {
            f4 s = red[t];
            #pragma unroll
            for (int p = 1; p < 32; ++p) s += red[t + 32 * p];
            reinterpret_cast<f4*>(part + ((size_t)b * NSTRIP + strip) * D_MODEL)[t] = s;
        }
    }
    gridbar(ctr);   // part complete, visible device-wide

    // ============ phase 2: every block redundantly computes wv[3][128] -> LDS ============
    if (t < 512) {
        int c = t >> 2, p = t & 3;
        f4 mv[8];
        #pragma unroll
        for (int d4 = 0; d4 < 8; ++d4) mv[d4] = (f4){0.f, 0.f, 0.f, 0.f};
        #pragma unroll
        for (int s = 0; s < NSTRIP; ++s) {
            const f4* ps = reinterpret_cast<const f4*>(part + ((size_t)c * NSTRIP + s) * D_MODEL + p * 32);
            #pragma unroll
            for (int d4 = 0; d4 < 8; ++d4) mv[d4] += ps[d4];
        }
        #pragma unroll
        for (int d4 = 0; d4 < 8; ++d4) mv[d4] *= (1.0f / (float)SEQ_L);

        float h[32];
        #pragma unroll
        for (int j = 0; j < 32; ++j) {
            const f4* w1r = reinterpret_cast<const f4*>(W1 + j * 128 + p * 32);
            f4 s4 = {0.f, 0.f, 0.f, 0.f};
            #pragma unroll
            for (int d4 = 0; d4 < 8; ++d4) s4 += mv[d4] * w1r[d4];
            float s = s4[0] + s4[1] + s4[2] + s4[3];
            s += __shfl_xor(s, 1);
            s += __shfl_xor(s, 2);               // full 128-dot across 4 partners
            s += b1[j];
            h[j] = 0.5f * s * (1.0f + erff(s * 0.70710678118654752f)); // exact gelu
        }
        if (p == 0) {
            float lg[3], mx = -1e30f;
            #pragma unroll
            for (int k = 0; k < 3; ++k) {
                float s = b2[k];
                #pragma unroll
                for (int j = 0; j < 32; ++j) s += h[j] * W2[k * 32 + j];
                lg[k] = s; mx = fmaxf(mx, s);
            }
            float e[3], den = 0.f;
            #pragma unroll
            for (int k = 0; k < 3; ++k) { e[k] = __expf(lg[k] - mx); den += e[k]; }
            float inv = 1.0f / den;
            #pragma unroll
            for (int k = 0; k < 3; ++k) wv_lds[k][c] = e[k] * inv;
        }
    }
    __syncthreads();   // wv_lds ready

    // ============ phase 3: conv + MFMA on own strip, 128-token tiles, 16 waves ============
    {
        int c4 = t & 31, rg = t >> 5;            // rg 0..31: rows rg*4..rg*4+3 of tile
        int lane = t & 63, wid = t >> 6;         // wid 0..15
        int r = lane & 15, q = lane >> 4, kb = q * 8;
        int hh = wid >> 3;                       // token half (0: rows 0-63, 1: 64-127)
        int co0 = (wid & 7) * 16;                // co block

        f4 w0 = *reinterpret_cast<const f4*>(&wv_lds[0][c4 * 4]);
        f4 w1 = *reinterpret_cast<const f4*>(&wv_lds[1][c4 * 4]);
        f4 w2 = *reinterpret_cast<const f4*>(&wv_lds[2][c4 * 4]);

        // Wc A-fragments from fp32 (L2/L3-hot), cvt in registers
        bf16x8 awc[4];
        #pragma unroll
        for (int kc = 0; kc < 4; ++kc) {
            const float* wr = Wc + (size_t)(co0 + r) * D_MODEL + kc * 32 + kb;
            f4 a = *reinterpret_cast<const f4*>(wr);
            f4 bb = *reinterpret_cast<const f4*>(wr + 4);
            bf16x8 fr;
            fr[0] = (short)f2bf(a[0]); fr[1] = (short)f2bf(a[1]);
            fr[2] = (short)f2bf(a[2]); fr[3] = (short)f2bf(a[3]);
            fr[4] = (short)f2bf(bb[0]); fr[5] = (short)f2bf(bb[1]);
            fr[6] = (short)f2bf(bb[2]); fr[7] = (short)f2bf(bb[3]);
            awc[kc] = fr;
        }

        f4 bcv = *reinterpret_cast<const f4*>(bc + co0 + q * 4);

        f4 R[6];
        if (sb == 0) load6<true>(xb, sb + rg * 4 - 1, c4, R);   // token -1 guard
        else         load6<false>(xb, sb + rg * 4 - 1, c4, R);

        for (int ht = 0; ht < STRIP / 128; ++ht) {   // 16 tiles of 128 tokens
            const int buf = ht & 1;
            int base = sb + ht * 128;
            // conv (consumes R) + LDS write
            #pragma unroll
            for (int j = 0; j < 4; ++j) {
                f4 y = R[j] * w0 + R[j + 1] * w1 + R[j + 2] * w2;
                ushort4 yb;
                yb.x = f2bf(y[0]); yb.y = f2bf(y[1]); yb.z = f2bf(y[2]); yb.w = f2bf(y[3]);
                *reinterpret_cast<ushort4*>(&y_lds[buf][rg * 4 + j][c4 * 4]) = yb;
            }
            // issue next tile's loads (fly under barrier+MFMA+stores)
            if (ht < STRIP / 128 - 1) {
                int nb = base + 128;
                if (nb + 128 == SEQ_L) load6<true>(xb, nb + rg * 4 - 1, c4, R);  // token 4096 guard
                else                   load6<false>(xb, nb + rg * 4 - 1, c4, R);
            }
            __syncthreads();   // y_lds[buf] visible

            // MFMA: wave = 64 tokens (half hh) x 16 co
            f32x4 acc[4];
            #pragma unroll
            for (int g = 0; g < 4; ++g) acc[g] = (f32x4){0.f, 0.f, 0.f, 0.f};
            #pragma unroll
            for (int g = 0; g < 4; ++g)
                #pragma unroll
                for (int kc = 0; kc < 4; ++kc) {
                    bf16x8 bv = *reinterpret_cast<const bf16x8*>(
                        &y_lds[buf][hh * 64 + g * 16 + r][kc * 32 + kb]);
                    acc[g] = __builtin_amdgcn_mfma_f32_16x16x32_bf16(awc[kc], bv, acc[g], 0, 0, 0);
                }

            #pragma unroll
            for (int g = 0; g < 4; ++g) {
                int tok = base + hh * 64 + g * 16 + r;
                *reinterpret_cast<f4*>(outb + (size_t)tok * D_MODEL + co0 + q * 4) = acc[g] + bcv;
            }
            __syncthreads();   // all waves done with y_lds[buf] before rewrite
        }
    }
}

extern "C" void kernel_launch(void* const* d_in, const int* in_sizes, int n_in,
                              void* d_out, int out_size, void* d_ws, size_t ws_size,
                              hipStream_t stream) {
    const float* x  = (const float*)d_in[0];
    const float* W1 = (const float*)d_in[1];
    const float* b1 = (const float*)d_in[2];
    const float* W2 = (const float*)d_in[3];
    const float* b2 = (const float*)d_in[4];
    const float* Wc = (const float*)d_in[5];
    const float* bc = (const float*)d_in[6];
    float* out = (float*)d_out;

    char* ws = (char*)d_ws;
    int* ctr = (int*)ws;                                      // barrier counter (zeroed below)
    float* part = (float*)(ws + 1024);                        // 128*2*128*4 = 128 KB

    hipMemsetAsync(ctr, 0, 128, stream);   // reset barrier counter every call (graph-legal)
    fused<<<NBLK, 1024, 0, stream>>>(x, W1, b1, W2, b2, Wc, bc, out, ctr, part);
}